// Round 2
// baseline (369.990 us; speedup 1.0000x reference)
//
#include <hip/hip_runtime.h>
#include <stdint.h>

#define C_IN 256
#define C_MID 64
#define KOFF 9

typedef __attribute__((ext_vector_type(8))) short bf16x8;   // 8 bf16 = 4 VGPRs
typedef __attribute__((ext_vector_type(4))) float f32x4;    // MFMA C/D
typedef __attribute__((ext_vector_type(4))) float float4v;

// fp32 -> bf16 round-to-nearest-even
__device__ inline unsigned short f2bf(float f) {
    union { float f; unsigned u; } x; x.f = f;
    unsigned r = x.u + 0x7FFFu + ((x.u >> 16) & 1u);
    return (unsigned short)(r >> 16);
}

// ---------------------------------------------------------------------------
// prep: fold BN scales into weights, transpose to B-fragment-friendly layouts,
// convert to bf16, zero the sentinel gather row.
//   w1t[n][k] = bf16(w1[k][n] * s1[n])          [64][256]
//   w2t[k][d][c] = bf16(w2[k][c][d] * s2[d])    [9][64][64]
//   w3t[e][c] = bf16(w3[c][e] * s3[e])          [256][64]
// ---------------------------------------------------------------------------
__global__ void prep_kernel(const float* __restrict__ w1, const float* __restrict__ s1,
                            const float* __restrict__ w2, const float* __restrict__ s2,
                            const float* __restrict__ w3, const float* __restrict__ s3,
                            unsigned short* __restrict__ w1t,
                            unsigned short* __restrict__ w2t,
                            unsigned short* __restrict__ w3t,
                            unsigned short* __restrict__ zrow) {
    int tid = blockIdx.x * blockDim.x + threadIdx.x;
    int stride = gridDim.x * blockDim.x;
    for (int i = tid; i < C_MID * C_IN; i += stride) {
        int n = i / C_IN, k = i % C_IN;
        w1t[i] = f2bf(w1[k * C_MID + n] * s1[n]);
    }
    for (int i = tid; i < KOFF * C_MID * C_MID; i += stride) {
        int k = i / (C_MID * C_MID);
        int r = i % (C_MID * C_MID);
        int d = r / C_MID, c = r % C_MID;
        w2t[i] = f2bf(w2[(k * C_MID + c) * C_MID + d] * s2[d]);
    }
    for (int i = tid; i < C_IN * C_MID; i += stride) {
        int e = i / C_MID, c = i % C_MID;
        w3t[i] = f2bf(w3[c * C_IN + e] * s3[e]);
    }
    for (int i = tid; i < C_MID; i += stride) zrow[i] = 0;
}

// ---------------------------------------------------------------------------
// conv1: out1[n][d] = relu(feat[n][:] @ w1[:, d] * s1[d] + b1[d]) as bf16.
// LDS-staged A tile: 64 rows x 256 cols loaded with fully-coalesced,
// fully-independent float4 loads (8 per thread over a contiguous 64 KB
// region), converted to bf16 into padded LDS (pitch 264 shorts breaks the
// 512 B bank stride), then 16x16x32 MFMA reads A-fragments via ds_read_b128.
// ---------------------------------------------------------------------------
__global__ __launch_bounds__(256, 4) void conv1_kernel(
    const float* __restrict__ feat, const unsigned short* __restrict__ w1t,
    const float* __restrict__ b1, unsigned short* __restrict__ out1, int N)
{
    __shared__ __align__(16) unsigned short sA[64 * 264];   // 33792 B

    int t = threadIdx.x;
    int wave = t >> 6;
    int lane = t & 63;
    int l15 = lane & 15;
    int quad = lane >> 4;
    int row_tile = blockIdx.x * 64;

    // ---- stage: 8 independent 32 B loads per thread, contiguous coverage ----
#pragma unroll
    for (int i = 0; i < 8; ++i) {
        int f = i * 2048 + t * 8;            // fp32 element index within tile
        int r = f >> 8;                      // 0..63
        int c = f & 255;
        int gr = row_tile + r;
        int grc = gr < N ? gr : (N - 1);
        const float4v* p = reinterpret_cast<const float4v*>(feat + (size_t)grc * C_IN + c);
        float4v a0 = p[0];
        float4v a1 = p[1];
        union { unsigned short s[8]; bf16x8 v; } ua;
#pragma unroll
        for (int j = 0; j < 4; ++j) { ua.s[j] = f2bf(a0[j]); ua.s[4 + j] = f2bf(a1[j]); }
        *reinterpret_cast<bf16x8*>(&sA[r * 264 + c]) = ua.v;
    }
    __syncthreads();

    const bf16x8* pb = reinterpret_cast<const bf16x8*>(w1t);
    float b1v[4];
#pragma unroll
    for (int ct = 0; ct < 4; ++ct) b1v[ct] = b1[ct * 16 + l15];

    int arow_lds = wave * 16 + l15;
    f32x4 acc[4] = {};
#pragma unroll
    for (int kk = 0; kk < 8; ++kk) {          // K = 256 in steps of 32
        bf16x8 fa = *reinterpret_cast<const bf16x8*>(&sA[arow_lds * 264 + kk * 32 + quad * 8]);
#pragma unroll
        for (int ct = 0; ct < 4; ++ct) {
            bf16x8 fb = pb[(ct * 16 + l15) * 32 + kk * 4 + quad];
            acc[ct] = __builtin_amdgcn_mfma_f32_16x16x32_bf16(fa, fb, acc[ct], 0, 0, 0);
        }
    }
    // C/D layout: col = lane&15 (+ct*16), row = quad*4 + reg
    int row_base = row_tile + wave * 16;
#pragma unroll
    for (int ct = 0; ct < 4; ++ct) {
#pragma unroll
        for (int reg = 0; reg < 4; ++reg) {
            int row = row_base + quad * 4 + reg;
            if (row < N) {
                float v = acc[ct][reg] + b1v[ct];
                out1[row * C_MID + ct * 16 + l15] = f2bf(fmaxf(v, 0.f));
            }
        }
    }
}

// ---------------------------------------------------------------------------
// conv2 + conv3 fused.
// Stage nbr indices for the whole 64-row tile into LDS (coalesced, dedup'd);
// issue ALL 18 gather loads per wave before any MFMA (max MLP), then conv2
// MFMA, LDS transpose (C-layout -> A-layout), conv3 MFMA, residual epilogue.
// ---------------------------------------------------------------------------
__global__ __launch_bounds__(256, 3) void conv23_kernel(
    const float* __restrict__ feat, const int* __restrict__ nbr,
    const unsigned short* __restrict__ out1, const unsigned short* __restrict__ w2t,
    const float* __restrict__ b2, const unsigned short* __restrict__ w3t,
    const float* __restrict__ b3, float* __restrict__ out, int N)
{
    __shared__ int sNbr[64 * KOFF];                          // 2304 B
    __shared__ __align__(16) unsigned short mid[4][16][72];  // 9216 B

    int t = threadIdx.x;
    int wave = t >> 6;
    int lane = t & 63;
    int l15 = lane & 15;
    int quad = lane >> 4;
    int row_tile = blockIdx.x * 64;

    // ---- stage rulebook slice for this tile (coalesced) ----
#pragma unroll
    for (int i = 0; i < 3; ++i) {
        int j = i * 256 + t;
        if (j < 64 * KOFF) {
            int g = row_tile * KOFF + j;
            sNbr[j] = (g < N * KOFF) ? nbr[g] : N;   // OOB rows -> sentinel (zeros)
        }
    }
    __syncthreads();

    int rt = wave * 16 + l15;      // row within tile for A-fragment
    int nb[KOFF];
#pragma unroll
    for (int k = 0; k < KOFF; ++k) nb[k] = sNbr[rt * KOFF + k];

    // ---- issue all gather loads up front ----
    bf16x8 ga[KOFF][2];
#pragma unroll
    for (int k = 0; k < KOFF; ++k) {
        const bf16x8* pg = reinterpret_cast<const bf16x8*>(out1 + (size_t)nb[k] * C_MID + quad * 8);
        ga[k][0] = pg[0];
        ga[k][1] = pg[4];
    }

    const bf16x8* pw2 = reinterpret_cast<const bf16x8*>(w2t);
    f32x4 acc2[4] = {};
#pragma unroll
    for (int k = 0; k < KOFF; ++k) {
#pragma unroll
        for (int kk = 0; kk < 2; ++kk) {
#pragma unroll
            for (int ct = 0; ct < 4; ++ct) {
                bf16x8 fb = pw2[k * 512 + (ct * 16 + l15) * 8 + kk * 4 + quad];
                acc2[ct] = __builtin_amdgcn_mfma_f32_16x16x32_bf16(ga[k][kk], fb, acc2[ct], 0, 0, 0);
            }
        }
    }
    // conv2 epilogue -> LDS (transpose C-layout to A-layout)
#pragma unroll
    for (int ct = 0; ct < 4; ++ct) {
        float bb = b2[ct * 16 + l15];
#pragma unroll
        for (int reg = 0; reg < 4; ++reg) {
            float v = fmaxf(acc2[ct][reg] + bb, 0.f);
            mid[wave][quad * 4 + reg][ct * 16 + l15] = f2bf(v);
        }
    }
    __syncthreads();

    const bf16x8* pw3 = reinterpret_cast<const bf16x8*>(w3t);
    f32x4 acc3[16] = {};
#pragma unroll
    for (int kk = 0; kk < 2; ++kk) {          // K = 64 in steps of 32
        bf16x8 fa = *reinterpret_cast<const bf16x8*>(&mid[wave][l15][kk * 32 + quad * 8]);
#pragma unroll
        for (int ct = 0; ct < 16; ++ct) {
            bf16x8 fb = pw3[(ct * 16 + l15) * 8 + kk * 4 + quad];
            acc3[ct] = __builtin_amdgcn_mfma_f32_16x16x32_bf16(fa, fb, acc3[ct], 0, 0, 0);
        }
    }
    // conv3 epilogue: bias + fp32 residual + relu
    int row_base = row_tile + wave * 16;
#pragma unroll
    for (int ct = 0; ct < 16; ++ct) {
        float bb = b3[ct * 16 + l15];
#pragma unroll
        for (int reg = 0; reg < 4; ++reg) {
            int row = row_base + quad * 4 + reg;
            if (row < N) {
                int o = row * C_IN + ct * 16 + l15;
                float v = acc3[ct][reg] + bb + feat[o];
                out[o] = fmaxf(v, 0.f);
            }
        }
    }
}

extern "C" void kernel_launch(void* const* d_in, const int* in_sizes, int n_in,
                              void* d_out, int out_size, void* d_ws, size_t ws_size,
                              hipStream_t stream) {
    const float* feat = (const float*)d_in[0];
    const int*   nbr  = (const int*)d_in[1];
    const float* w1   = (const float*)d_in[2];
    const float* s1   = (const float*)d_in[3];
    const float* b1   = (const float*)d_in[4];
    const float* w2   = (const float*)d_in[5];
    const float* s2   = (const float*)d_in[6];
    const float* b2   = (const float*)d_in[7];
    const float* w3   = (const float*)d_in[8];
    const float* s3   = (const float*)d_in[9];
    const float* b3   = (const float*)d_in[10];
    float* out = (float*)d_out;
    int N = in_sizes[0] / C_IN;

    char* ws = (char*)d_ws;
    unsigned short* w1t  = (unsigned short*)(ws);                    // 32768 B
    unsigned short* w2t  = (unsigned short*)(ws + 32768);            // 73728 B
    unsigned short* w3t  = (unsigned short*)(ws + 32768 + 73728);    // 32768 B
    unsigned short* out1 = (unsigned short*)(ws + 139264);           // (N+1)*64*2 B

    prep_kernel<<<80, 256, 0, stream>>>(w1, s1, w2, s2, w3, s3, w1t, w2t, w3t,
                                        out1 + (size_t)N * C_MID);
    int nblk = (N + 63) / 64;
    conv1_kernel<<<nblk, 256, 0, stream>>>(feat, w1t, b1, out1, N);
    conv23_kernel<<<nblk, 256, 0, stream>>>(feat, nbr, out1, w2t, b2, w3t, b3, out, N);
}

// Round 5
// 310.855 us; speedup vs baseline: 1.1902x; 1.1902x over previous
//
#include <hip/hip_runtime.h>
#include <stdint.h>

#define C_IN 256
#define C_MID 64
#define KOFF 9

typedef __attribute__((ext_vector_type(8))) short bf16x8;   // 8 bf16 = 4 VGPRs
typedef __attribute__((ext_vector_type(4))) float f32x4;    // MFMA C/D
typedef __attribute__((ext_vector_type(4))) float float4v;

// fp32 -> bf16 round-to-nearest-even
__device__ inline unsigned short f2bf(float f) {
    union { float f; unsigned u; } x; x.f = f;
    unsigned r = x.u + 0x7FFFu + ((x.u >> 16) & 1u);
    return (unsigned short)(r >> 16);
}

// ---------------------------------------------------------------------------
// prep: fold BN scales into weights, transpose to B-fragment layouts, bf16,
// zero the sentinel gather row.
//   w1t[n][k] = bf16(w1[k][n] * s1[n])          [64][256]   16384 shorts
//   w2t[k][d][c] = bf16(w2[k][c][d] * s2[d])    [9][64][64] 36864 shorts
//   w3t[e][c] = bf16(w3[c][e] * s3[e])          [256][64]   16384 shorts
// ---------------------------------------------------------------------------
__global__ void prep_kernel(const float* __restrict__ w1, const float* __restrict__ s1,
                            const float* __restrict__ w2, const float* __restrict__ s2,
                            const float* __restrict__ w3, const float* __restrict__ s3,
                            unsigned short* __restrict__ w1t,
                            unsigned short* __restrict__ w2t,
                            unsigned short* __restrict__ w3t,
                            unsigned short* __restrict__ zrow) {
    int tid = blockIdx.x * blockDim.x + threadIdx.x;
    int stride = gridDim.x * blockDim.x;
    for (int i = tid; i < C_MID * C_IN; i += stride) {
        int n = i / C_IN, k = i % C_IN;
        w1t[i] = f2bf(w1[k * C_MID + n] * s1[n]);
    }
    for (int i = tid; i < KOFF * C_MID * C_MID; i += stride) {
        int k = i / (C_MID * C_MID);
        int r = i % (C_MID * C_MID);
        int d = r / C_MID, c = r % C_MID;
        w2t[i] = f2bf(w2[(k * C_MID + c) * C_MID + d] * s2[d]);
    }
    for (int i = tid; i < C_IN * C_MID; i += stride) {
        int e = i / C_MID, c = i % C_MID;
        w3t[i] = f2bf(w3[c * C_IN + e] * s3[e]);
    }
    for (int i = tid; i < C_MID; i += stride) zrow[i] = 0;
}

// ---------------------------------------------------------------------------
// conv1. A-tile staged to LDS (coalesced float4, pitch 264 breaks bank
// aliasing), w1t staged to LDS swizzled so B-fragment ds_read_b128 is
// bank-uniform. LDS total 66560 B -> 2 blocks/CU.
// ---------------------------------------------------------------------------
__global__ __launch_bounds__(256, 2) void conv1_kernel(
    const float* __restrict__ feat, const unsigned short* __restrict__ w1t,
    const float* __restrict__ b1, unsigned short* __restrict__ out1, int N)
{
    __shared__ __align__(16) unsigned short sA[64 * 264];    // 16896 shorts = 33792 B
    __shared__ __align__(16) unsigned short sW1[16384];      // 16384 shorts = 32768 B

    int t = threadIdx.x;
    int wave = t >> 6;
    int lane = t & 63;
    int l15 = lane & 15;
    int quad = lane >> 4;
    int row_tile = blockIdx.x * 64;

    // ---- stage A: 8 independent coalesced 32 B loads per thread ----
#pragma unroll
    for (int i = 0; i < 8; ++i) {
        int f = i * 2048 + t * 8;
        int r = f >> 8;
        int c = f & 255;
        int gr = row_tile + r;
        int grc = gr < N ? gr : (N - 1);
        const float4v* p = reinterpret_cast<const float4v*>(feat + (size_t)grc * C_IN + c);
        float4v a0 = p[0];
        float4v a1 = p[1];
        union { unsigned short s[8]; bf16x8 v; } ua;
#pragma unroll
        for (int j = 0; j < 4; ++j) { ua.s[j] = f2bf(a0[j]); ua.s[4 + j] = f2bf(a1[j]); }
        *reinterpret_cast<bf16x8*>(&sA[r * 264 + c]) = ua.v;
    }
    // ---- stage w1t: 2048 chunks / 256 thr = 8 each ----
    const bf16x8* w1c = reinterpret_cast<const bf16x8*>(w1t);
    bf16x8* sW1c = reinterpret_cast<bf16x8*>(sW1);
#pragma unroll
    for (int it = 0; it < 8; ++it) {
        int s = it * 256 + t;
        int l = s & 15, ct = (s >> 4) & 3, q = (s >> 6) & 3, kk = s >> 8;
        sW1c[s] = w1c[(ct * 16 + l) * 32 + kk * 4 + q];
    }
    __syncthreads();

    float b1v[4];
#pragma unroll
    for (int ct = 0; ct < 4; ++ct) b1v[ct] = b1[ct * 16 + l15];

    int arow = wave * 16 + l15;
    f32x4 acc[4] = {};
#pragma unroll
    for (int kk = 0; kk < 8; ++kk) {
        bf16x8 fa = *reinterpret_cast<const bf16x8*>(&sA[arow * 264 + kk * 32 + quad * 8]);
#pragma unroll
        for (int ct = 0; ct < 4; ++ct) {
            bf16x8 fb = sW1c[((kk * 4 + quad) * 4 + ct) * 16 + l15];
            acc[ct] = __builtin_amdgcn_mfma_f32_16x16x32_bf16(fa, fb, acc[ct], 0, 0, 0);
        }
    }
    int row_base = row_tile + wave * 16;
#pragma unroll
    for (int ct = 0; ct < 4; ++ct) {
#pragma unroll
        for (int reg = 0; reg < 4; ++reg) {
            int row = row_base + quad * 4 + reg;
            if (row < N) {
                float v = acc[ct][reg] + b1v[ct];
                out1[row * C_MID + ct * 16 + l15] = f2bf(fmaxf(v, 0.f));
            }
        }
    }
}

// ---------------------------------------------------------------------------
// conv2 + conv3 fused, phase-shared LDS weight buffer (R4 bug: sW2 was sized
// in bytes not shorts -> LDS OOB; now full 36864-short buffer):
//   phase A: sWB holds all of w2t (4608 chunks, 73728 B); 18 pinned gathers;
//            conv2 MFMAs.
//   barrier (all waves done reading w2)
//   phase B: mid -> sWB tail (bytes 64512..73728); w3t restaged into chunks
//            0..2047 (disjoint); barrier; conv3 reads w3 + mid.
// LDS total 76032 B -> 2 blocks/CU.
// ---------------------------------------------------------------------------
__global__ __launch_bounds__(256, 2) void conv23_kernel(
    const float* __restrict__ feat, const int* __restrict__ nbr,
    const unsigned short* __restrict__ out1, const unsigned short* __restrict__ w2t,
    const float* __restrict__ b2, const unsigned short* __restrict__ w3t,
    const float* __restrict__ b3, float* __restrict__ out, int N)
{
    __shared__ __align__(16) unsigned short sWB[36864];      // 73728 B
    __shared__ int sNbr[64 * KOFF];                          // 2304 B

    int t = threadIdx.x;
    int wave = t >> 6;
    int lane = t & 63;
    int l15 = lane & 15;
    int quad = lane >> 4;
    int row_tile = blockIdx.x * 64;

    bf16x8* sWBc = reinterpret_cast<bf16x8*>(sWB);

    // ---- phase A stage: all of w2t, 4608 chunks / 256 thr = 18 each ----
    const bf16x8* w2c = reinterpret_cast<const bf16x8*>(w2t);
#pragma unroll
    for (int it = 0; it < 18; ++it) {
        int s = it * 256 + t;
        int l = s & 15, ct = (s >> 4) & 3, q = (s >> 6) & 3, kk = (s >> 8) & 1, k = s >> 9;
        sWBc[s] = w2c[k * 512 + (ct * 16 + l) * 8 + kk * 4 + q];
    }
    // ---- stage rulebook slice ----
#pragma unroll
    for (int i = 0; i < 3; ++i) {
        int j = i * 256 + t;
        if (j < 64 * KOFF) {
            int g = row_tile * KOFF + j;
            sNbr[j] = (g < N * KOFF) ? nbr[g] : N;
        }
    }
    __syncthreads();

    int rt = wave * 16 + l15;
    int nb[KOFF];
#pragma unroll
    for (int k = 0; k < KOFF; ++k) nb[k] = sNbr[rt * KOFF + k];

    // ---- issue ALL 18 gathers, pin them in place ----
    bf16x8 ga[KOFF][2];
#pragma unroll
    for (int k = 0; k < KOFF; ++k) {
        const bf16x8* pg = reinterpret_cast<const bf16x8*>(out1 + (size_t)nb[k] * C_MID + quad * 8);
        ga[k][0] = pg[0];
        ga[k][1] = pg[4];
    }
    __builtin_amdgcn_sched_barrier(0);

    f32x4 acc2[4] = {};
#pragma unroll
    for (int k = 0; k < KOFF; ++k) {
#pragma unroll
        for (int kk = 0; kk < 2; ++kk) {
#pragma unroll
            for (int ct = 0; ct < 4; ++ct) {
                bf16x8 fb = sWBc[((k * 2 + kk) * 4 + quad) * 64 + ct * 16 + l15];
                acc2[ct] = __builtin_amdgcn_mfma_f32_16x16x32_bf16(ga[k][kk], fb, acc2[ct], 0, 0, 0);
            }
        }
    }
    __syncthreads();   // all waves done reading w2 before tail is overwritten

    // ---- phase B: mid into sWB tail; restage w3 into chunks 0..2047 ----
    unsigned short* mid = &sWB[32256];   // [4][16][72] shorts, bytes 64512..73727
#pragma unroll
    for (int ct = 0; ct < 4; ++ct) {
        float bb = b2[ct * 16 + l15];
#pragma unroll
        for (int reg = 0; reg < 4; ++reg) {
            float v = fmaxf(acc2[ct][reg] + bb, 0.f);
            mid[(wave * 16 + quad * 4 + reg) * 72 + ct * 16 + l15] = f2bf(v);
        }
    }
    const bf16x8* w3c = reinterpret_cast<const bf16x8*>(w3t);
#pragma unroll
    for (int it = 0; it < 8; ++it) {
        int s = it * 256 + t;
        int l = s & 15, c2 = (s >> 4) & 15, q = (s >> 8) & 3, kk = (s >> 10) & 1;
        sWBc[s] = w3c[(c2 * 16 + l) * 8 + kk * 4 + q];
    }
    __syncthreads();   // mid + w3 visible (orders cross-lane LDS RAW — R3 lesson)

    f32x4 acc3[16] = {};
#pragma unroll
    for (int kk = 0; kk < 2; ++kk) {
        bf16x8 fa = *reinterpret_cast<const bf16x8*>(
            &mid[(wave * 16 + l15) * 72 + kk * 32 + quad * 8]);
#pragma unroll
        for (int c2 = 0; c2 < 16; ++c2) {
            bf16x8 fb = sWBc[((kk * 4 + quad) * 16 + c2) * 16 + l15];
            acc3[c2] = __builtin_amdgcn_mfma_f32_16x16x32_bf16(fa, fb, acc3[c2], 0, 0, 0);
        }
    }
    // conv3 epilogue: bias + fp32 residual + relu
    int row_base = row_tile + wave * 16;
#pragma unroll
    for (int c2 = 0; c2 < 16; ++c2) {
        float bb = b3[c2 * 16 + l15];
#pragma unroll
        for (int reg = 0; reg < 4; ++reg) {
            int row = row_base + quad * 4 + reg;
            if (row < N) {
                int o = row * C_IN + c2 * 16 + l15;
                float v = acc3[c2][reg] + bb + feat[o];
                out[o] = fmaxf(v, 0.f);
            }
        }
    }
}

extern "C" void kernel_launch(void* const* d_in, const int* in_sizes, int n_in,
                              void* d_out, int out_size, void* d_ws, size_t ws_size,
                              hipStream_t stream) {
    const float* feat = (const float*)d_in[0];
    const int*   nbr  = (const int*)d_in[1];
    const float* w1   = (const float*)d_in[2];
    const float* s1   = (const float*)d_in[3];
    const float* b1   = (const float*)d_in[4];
    const float* w2   = (const float*)d_in[5];
    const float* s2   = (const float*)d_in[6];
    const float* b2   = (const float*)d_in[7];
    const float* w3   = (const float*)d_in[8];
    const float* s3   = (const float*)d_in[9];
    const float* b3   = (const float*)d_in[10];
    float* out = (float*)d_out;
    int N = in_sizes[0] / C_IN;

    char* ws = (char*)d_ws;
    unsigned short* w1t  = (unsigned short*)(ws);                    // 32768 B
    unsigned short* w2t  = (unsigned short*)(ws + 32768);            // 73728 B
    unsigned short* w3t  = (unsigned short*)(ws + 32768 + 73728);    // 32768 B
    unsigned short* out1 = (unsigned short*)(ws + 139264);           // (N+1)*64*2 B

    prep_kernel<<<80, 256, 0, stream>>>(w1, s1, w2, s2, w3, s3, w1t, w2t, w3t,
                                        out1 + (size_t)N * C_MID);
    int nblk = (N + 63) / 64;
    conv1_kernel<<<nblk, 256, 0, stream>>>(feat, w1t, b1, out1, N);
    conv23_kernel<<<nblk, 256, 0, stream>>>(feat, nbr, out1, w2t, b2, w3t, b3, out, N);
}

// Round 6
// 263.817 us; speedup vs baseline: 1.4025x; 1.1783x over previous
//
#include <hip/hip_runtime.h>
#include <stdint.h>

#define C_IN 256
#define C_MID 64
#define KOFF 9

typedef __attribute__((ext_vector_type(8))) short bf16x8;   // 8 bf16 = 4 VGPRs
typedef __attribute__((ext_vector_type(4))) short short4v;  // 8 B packed bf16x4
typedef __attribute__((ext_vector_type(4))) float f32x4;    // MFMA C/D
typedef __attribute__((ext_vector_type(4))) float float4v;

// fp32 -> bf16 round-to-nearest-even
__device__ inline unsigned short f2bf(float f) {
    union { float f; unsigned u; } x; x.f = f;
    unsigned r = x.u + 0x7FFFu + ((x.u >> 16) & 1u);
    return (unsigned short)(r >> 16);
}

// ---------------------------------------------------------------------------
// prep (unchanged layouts — they serve as A-operand rows after the role swap):
//   w1t[n][k] = bf16(w1[k][n] * s1[n])          [64][256]   16384 shorts
//   w2t[k][d][c] = bf16(w2[k][c][d] * s2[d])    [9][64][64] 36864 shorts
//   w3t[e][c] = bf16(w3[c][e] * s3[e])          [256][64]   16384 shorts
// ---------------------------------------------------------------------------
__global__ void prep_kernel(const float* __restrict__ w1, const float* __restrict__ s1,
                            const float* __restrict__ w2, const float* __restrict__ s2,
                            const float* __restrict__ w3, const float* __restrict__ s3,
                            unsigned short* __restrict__ w1t,
                            unsigned short* __restrict__ w2t,
                            unsigned short* __restrict__ w3t,
                            unsigned short* __restrict__ zrow) {
    int tid = blockIdx.x * blockDim.x + threadIdx.x;
    int stride = gridDim.x * blockDim.x;
    for (int i = tid; i < C_MID * C_IN; i += stride) {
        int n = i / C_IN, k = i % C_IN;
        w1t[i] = f2bf(w1[k * C_MID + n] * s1[n]);
    }
    for (int i = tid; i < KOFF * C_MID * C_MID; i += stride) {
        int k = i / (C_MID * C_MID);
        int r = i % (C_MID * C_MID);
        int d = r / C_MID, c = r % C_MID;
        w2t[i] = f2bf(w2[(k * C_MID + c) * C_MID + d] * s2[d]);
    }
    for (int i = tid; i < C_IN * C_MID; i += stride) {
        int e = i / C_MID, c = i % C_MID;
        w3t[i] = f2bf(w3[c * C_IN + e] * s3[e]);
    }
    for (int i = tid; i < C_MID; i += stride) zrow[i] = 0;
}

// ---------------------------------------------------------------------------
// conv1, role-swapped: D[d][site] = W1·F. Weights = A (from LDS, swizzled),
// feat rows = B (pinned global float4 loads, dense 128 B runs per site).
// No A-tile LDS -> 32.8 KB LDS -> 4 blocks/CU. Lane owns site l15, channels
// in runs of 4 -> 8 B out1 stores.
// ---------------------------------------------------------------------------
__global__ __launch_bounds__(256, 4) void conv1_kernel(
    const float* __restrict__ feat, const unsigned short* __restrict__ w1t,
    const float* __restrict__ b1, unsigned short* __restrict__ out1, int N)
{
    __shared__ __align__(16) unsigned short sW1[16384];      // 32768 B

    int t = threadIdx.x;
    int wave = t >> 6;
    int lane = t & 63;
    int l15 = lane & 15;
    int quad = lane >> 4;
    int row_tile = blockIdx.x * 64;
    int site = row_tile + wave * 16 + l15;
    int sitec = site < N ? site : (N - 1);

    // ---- stage w1t swizzled (same swizzle as R5) ----
    const bf16x8* w1c = reinterpret_cast<const bf16x8*>(w1t);
    bf16x8* sW1c = reinterpret_cast<bf16x8*>(sW1);
#pragma unroll
    for (int it = 0; it < 8; ++it) {
        int s = it * 256 + t;
        int l = s & 15, ct = (s >> 4) & 3, q = (s >> 6) & 3, kk = s >> 8;
        sW1c[s] = w1c[(ct * 16 + l) * 32 + kk * 4 + q];
    }

    // ---- pin all 16 feat float4 loads (B-fragments) ----
    float4v fr[16];
#pragma unroll
    for (int kk = 0; kk < 8; ++kk) {
        const float4v* p = reinterpret_cast<const float4v*>(
            feat + (size_t)sitec * C_IN + kk * 32 + quad * 8);
        fr[kk * 2] = p[0];
        fr[kk * 2 + 1] = p[1];
    }
    __builtin_amdgcn_sched_barrier(0);
    __syncthreads();

    f32x4 acc[4] = {};
#pragma unroll
    for (int kk = 0; kk < 8; ++kk) {
        union { unsigned short s[8]; bf16x8 v; } ua;
#pragma unroll
        for (int j = 0; j < 4; ++j) {
            ua.s[j] = f2bf(fr[kk * 2][j]);
            ua.s[4 + j] = f2bf(fr[kk * 2 + 1][j]);
        }
#pragma unroll
        for (int ct = 0; ct < 4; ++ct) {
            bf16x8 fa = sW1c[((kk * 4 + quad) * 4 + ct) * 16 + l15];  // A: w1 rows
            acc[ct] = __builtin_amdgcn_mfma_f32_16x16x32_bf16(fa, ua.v, acc[ct], 0, 0, 0);
        }
    }
    // D: col=l15 -> site, row=quad*4+reg -> channel ct*16+quad*4+reg
    if (site < N) {
#pragma unroll
        for (int ct = 0; ct < 4; ++ct) {
            const float4v* bp = reinterpret_cast<const float4v*>(b1 + ct * 16 + quad * 4);
            float4v bb = bp[0];
            union { unsigned short s[4]; short4v v; } o;
#pragma unroll
            for (int reg = 0; reg < 4; ++reg)
                o.s[reg] = f2bf(fmaxf(acc[ct][reg] + bb[reg], 0.f));
            *reinterpret_cast<short4v*>(out1 + (size_t)site * C_MID + ct * 16 + quad * 4) = o.v;
        }
    }
}

// ---------------------------------------------------------------------------
// conv2+conv3, role-swapped. Lane owns site l15 and channel runs of 4.
// Phase-shared LDS weight buffer (w2 -> [mid tail | w3 head]).
// Pinned: 18 gathers + 16 float4 residual loads (issued before conv2).
// Epilogue: 16 float4 stores, fully line-coalesced.
// ---------------------------------------------------------------------------
__global__ __launch_bounds__(256, 2) void conv23_kernel(
    const float* __restrict__ feat, const int* __restrict__ nbr,
    const unsigned short* __restrict__ out1, const unsigned short* __restrict__ w2t,
    const float* __restrict__ b2, const unsigned short* __restrict__ w3t,
    const float* __restrict__ b3, float* __restrict__ out, int N)
{
    __shared__ __align__(16) unsigned short sWB[36864];      // 73728 B
    __shared__ int sNbr[64 * KOFF];                          // 2304 B

    int t = threadIdx.x;
    int wave = t >> 6;
    int lane = t & 63;
    int l15 = lane & 15;
    int quad = lane >> 4;
    int row_tile = blockIdx.x * 64;
    int site = row_tile + wave * 16 + l15;
    int sitec = site < N ? site : (N - 1);

    bf16x8* sWBc = reinterpret_cast<bf16x8*>(sWB);

    // ---- phase A stage: all of w2t (4608 chunks), swizzled as R5 ----
    const bf16x8* w2c = reinterpret_cast<const bf16x8*>(w2t);
#pragma unroll
    for (int it = 0; it < 18; ++it) {
        int s = it * 256 + t;
        int l = s & 15, ct = (s >> 4) & 3, q = (s >> 6) & 3, kk = (s >> 8) & 1, k = s >> 9;
        sWBc[s] = w2c[k * 512 + (ct * 16 + l) * 8 + kk * 4 + q];
    }
    // ---- stage rulebook slice ----
#pragma unroll
    for (int i = 0; i < 3; ++i) {
        int j = i * 256 + t;
        if (j < 64 * KOFF) {
            int g = row_tile * KOFF + j;
            sNbr[j] = (g < N * KOFF) ? nbr[g] : N;
        }
    }
    __syncthreads();

    int rt = wave * 16 + l15;
    int nb[KOFF];
#pragma unroll
    for (int k = 0; k < KOFF; ++k) nb[k] = sNbr[rt * KOFF + k];

    // ---- pin 18 gathers (B-fragments) + 16 residual float4 loads ----
    bf16x8 ga[KOFF][2];
#pragma unroll
    for (int k = 0; k < KOFF; ++k) {
        const bf16x8* pg = reinterpret_cast<const bf16x8*>(out1 + (size_t)nb[k] * C_MID + quad * 8);
        ga[k][0] = pg[0];
        ga[k][1] = pg[4];
    }
    float4v rf[16];
#pragma unroll
    for (int c2 = 0; c2 < 16; ++c2)
        rf[c2] = *reinterpret_cast<const float4v*>(
            feat + (size_t)sitec * C_IN + c2 * 16 + quad * 4);
    __builtin_amdgcn_sched_barrier(0);

    f32x4 acc2[4] = {};
#pragma unroll
    for (int k = 0; k < KOFF; ++k) {
#pragma unroll
        for (int kk = 0; kk < 2; ++kk) {
#pragma unroll
            for (int ct = 0; ct < 4; ++ct) {
                bf16x8 fa = sWBc[((k * 2 + kk) * 4 + quad) * 64 + ct * 16 + l15]; // A: w2 rows
                acc2[ct] = __builtin_amdgcn_mfma_f32_16x16x32_bf16(fa, ga[k][kk], acc2[ct], 0, 0, 0);
            }
        }
    }
    __syncthreads();   // all waves done reading w2 before overlay

    // ---- phase B: mid (pitch 80, 16B-aligned rows) at sWB tail; w3 head ----
    unsigned short* mid = &sWB[31744];   // [64 sites][80] shorts = 10240 B
#pragma unroll
    for (int ct = 0; ct < 4; ++ct) {
        const float4v* bp = reinterpret_cast<const float4v*>(b2 + ct * 16 + quad * 4);
        float4v bb = bp[0];
        union { unsigned short s[4]; short4v v; } o;
#pragma unroll
        for (int reg = 0; reg < 4; ++reg)
            o.s[reg] = f2bf(fmaxf(acc2[ct][reg] + bb[reg], 0.f));
        *reinterpret_cast<short4v*>(&mid[(wave * 16 + l15) * 80 + ct * 16 + quad * 4]) = o.v;
    }
    const bf16x8* w3c = reinterpret_cast<const bf16x8*>(w3t);
#pragma unroll
    for (int it = 0; it < 8; ++it) {
        int s = it * 256 + t;
        int l = s & 15, c2 = (s >> 4) & 15, q = (s >> 8) & 3, kk = (s >> 10) & 1;
        sWBc[s] = w3c[(c2 * 16 + l) * 8 + kk * 4 + q];
    }
    __syncthreads();   // mid + w3 visible (cross-lane LDS RAW — R3 lesson)

    f32x4 acc3[16] = {};
#pragma unroll
    for (int kk = 0; kk < 2; ++kk) {
        bf16x8 fb = *reinterpret_cast<const bf16x8*>(
            &mid[(wave * 16 + l15) * 80 + kk * 32 + quad * 8]);   // B: own site's mid row
#pragma unroll
        for (int c2 = 0; c2 < 16; ++c2) {
            bf16x8 fa = sWBc[((kk * 4 + quad) * 16 + c2) * 16 + l15];  // A: w3 rows
            acc3[c2] = __builtin_amdgcn_mfma_f32_16x16x32_bf16(fa, fb, acc3[c2], 0, 0, 0);
        }
    }
    // ---- epilogue: bias + pinned fp32 residual + relu, float4 stores ----
    if (site < N) {
#pragma unroll
        for (int c2 = 0; c2 < 16; ++c2) {
            const float4v* bp = reinterpret_cast<const float4v*>(b3 + c2 * 16 + quad * 4);
            float4v bb = bp[0];
            float4v o;
#pragma unroll
            for (int reg = 0; reg < 4; ++reg)
                o[reg] = fmaxf(acc3[c2][reg] + bb[reg] + rf[c2][reg], 0.f);
            *reinterpret_cast<float4v*>(out + (size_t)site * C_IN + c2 * 16 + quad * 4) = o;
        }
    }
}

extern "C" void kernel_launch(void* const* d_in, const int* in_sizes, int n_in,
                              void* d_out, int out_size, void* d_ws, size_t ws_size,
                              hipStream_t stream) {
    const float* feat = (const float*)d_in[0];
    const int*   nbr  = (const int*)d_in[1];
    const float* w1   = (const float*)d_in[2];
    const float* s1   = (const float*)d_in[3];
    const float* b1   = (const float*)d_in[4];
    const float* w2   = (const float*)d_in[5];
    const float* s2   = (const float*)d_in[6];
    const float* b2   = (const float*)d_in[7];
    const float* w3   = (const float*)d_in[8];
    const float* s3   = (const float*)d_in[9];
    const float* b3   = (const float*)d_in[10];
    float* out = (float*)d_out;
    int N = in_sizes[0] / C_IN;

    char* ws = (char*)d_ws;
    unsigned short* w1t  = (unsigned short*)(ws);                    // 32768 B
    unsigned short* w2t  = (unsigned short*)(ws + 32768);            // 73728 B
    unsigned short* w3t  = (unsigned short*)(ws + 32768 + 73728);    // 32768 B
    unsigned short* out1 = (unsigned short*)(ws + 139264);           // (N+1)*64*2 B

    prep_kernel<<<80, 256, 0, stream>>>(w1, s1, w2, s2, w3, s3, w1t, w2t, w3t,
                                        out1 + (size_t)N * C_MID);
    int nblk = (N + 63) / 64;
    conv1_kernel<<<nblk, 256, 0, stream>>>(feat, w1t, b1, out1, N);
    conv23_kernel<<<nblk, 256, 0, stream>>>(feat, nbr, out1, w2t, b2, w3t, b3, out, N);
}